// Round 2
// baseline (194.152 us; speedup 1.0000x reference)
//
#include <hip/hip_runtime.h>
#include <hip/hip_bf16.h>

#define N_ROWS 4096
#define TWO_N 8192
#define DIM 512
#define BK 32
#define INV_T 14.285714285714286f          // 1/0.07
#define LOG2E 1.4426950408889634f
#define C_LOG2E 20.60992915555662f          // (1/0.07)*log2(e)
#define INV_SQRT_T 3.7796447300922722f      // 1/sqrt(0.07)

typedef __bf16 bf16x8 __attribute__((ext_vector_type(8)));
typedef float f32x4 __attribute__((ext_vector_type(4)));

#define ASYNC_COPY16(gp, lp)                                                     \
  __builtin_amdgcn_global_load_lds((const __attribute__((address_space(1))) void*)(gp), \
                                   (__attribute__((address_space(3))) void*)(lp), 16, 0, 0)

__device__ __forceinline__ float block_reduce_sum(float v, float* red) {
  int t = threadIdx.x;
#pragma unroll
  for (int off = 32; off > 0; off >>= 1) v += __shfl_down(v, off, 64);
  if ((t & 63) == 0) red[t >> 6] = v;
  __syncthreads();
  return red[0] + red[1] + red[2] + red[3];
}

// One block per row: compute norm, store bf16 z_hat * (1/sqrt(T)), store scale.
__global__ void k_normalize(const float* __restrict__ z1, const float* __restrict__ z2,
                            __hip_bfloat16* __restrict__ zn, float* __restrict__ scales) {
  __shared__ float red[4];
  const int r = blockIdx.x, t = threadIdx.x;
  const float* src = (r < N_ROWS) ? (z1 + (size_t)r * DIM) : (z2 + (size_t)(r - N_ROWS) * DIM);
  float a = src[t], b = src[t + 256];
  float ss = block_reduce_sum(a * a + b * b, red);
  float norm = fmaxf(sqrtf(ss), 1e-8f);
  float scale = INV_SQRT_T / norm;
  zn[(size_t)r * DIM + t]       = __float2bfloat16(a * scale);
  zn[(size_t)r * DIM + t + 256] = __float2bfloat16(b * scale);
  if (t == 0) scales[r] = scale;
}

// Positives in fp32: pos_i = (z1_i . z2_i) * scale_i * scale_{i+N}  == cos/T
__global__ void k_pos(const float* __restrict__ z1, const float* __restrict__ z2,
                      const float* __restrict__ scales, float* __restrict__ posbuf) {
  __shared__ float red[4];
  const int r = blockIdx.x, t = threadIdx.x;
  const float* p1 = z1 + (size_t)r * DIM;
  const float* p2 = z2 + (size_t)r * DIM;
  float d = p1[t] * p2[t] + p1[t + 256] * p2[t + 256];
  float dot = block_reduce_sum(d, red);
  if (t == 0) posbuf[r] = dot * scales[r] * scales[r + N_ROWS];
}

// Flash-LSE GEMM: 128x128 tile of sim = Zn * Zn^T, epilogue accumulates
// sum_j exp(s_ij - C) into rowsum via atomicAdd. Diagonal masked to 0.
__global__ __launch_bounds__(256, 2) void k_lse(const __hip_bfloat16* __restrict__ Zn,
                                                float* __restrict__ rowsum) {
  __shared__ char smem[16384] __attribute__((aligned(16)));
  char* sA = smem;
  char* sB = smem + 8192;
  const int tid  = threadIdx.x;
  const int wave = tid >> 6;
  const int lane = tid & 63;
  const int cl   = lane & 15;
  const int q    = lane >> 4;
  const int rt = blockIdx.y, ct = blockIdx.x;
  const int wr = (wave >> 1) * 64;   // wave's row offset in tile
  const int wc = (wave & 1) * 64;    // wave's col offset in tile

  // staging granules: 512 granules of 16B per 128x32 tile; thread t owns t and t+256
  const int g0 = tid, g1 = tid + 256;
  const size_t aoff0 = (size_t)(rt * 128 + (g0 >> 2)) * DIM + (g0 & 3) * 8;
  const size_t aoff1 = (size_t)(rt * 128 + (g1 >> 2)) * DIM + (g1 & 3) * 8;
  const size_t boff0 = (size_t)(ct * 128 + (g0 >> 2)) * DIM + (g0 & 3) * 8;
  const size_t boff1 = (size_t)(ct * 128 + (g1 >> 2)) * DIM + (g1 & 3) * 8;
  char* ldsA0 = sA + wave * 1024;
  char* ldsA1 = sA + 4096 + wave * 1024;
  char* ldsB0 = sB + wave * 1024;
  char* ldsB1 = sB + 4096 + wave * 1024;

  f32x4 acc[4][4] = {};

  for (int ks = 0; ks < DIM / BK; ks++) {
    const int ko = ks * BK;
    ASYNC_COPY16(Zn + aoff0 + ko, ldsA0);
    ASYNC_COPY16(Zn + aoff1 + ko, ldsA1);
    ASYNC_COPY16(Zn + boff0 + ko, ldsB0);
    ASYNC_COPY16(Zn + boff1 + ko, ldsB1);
    __syncthreads();

    bf16x8 af[4], bfr[4];
#pragma unroll
    for (int i = 0; i < 4; i++)
      af[i] = *reinterpret_cast<const bf16x8*>(sA + ((wr + i * 16 + cl) * BK + q * 8) * 2);
#pragma unroll
    for (int j = 0; j < 4; j++)
      bfr[j] = *reinterpret_cast<const bf16x8*>(sB + ((wc + j * 16 + cl) * BK + q * 8) * 2);
#pragma unroll
    for (int i = 0; i < 4; i++)
#pragma unroll
      for (int j = 0; j < 4; j++)
        acc[i][j] = __builtin_amdgcn_mfma_f32_16x16x32_bf16(af[i], bfr[j], acc[i][j], 0, 0, 0);
    __syncthreads();
  }

  // Epilogue: e = exp(s - C), diagonal masked, accumulate per-row partial sums.
  const bool diagw = (rt == ct) && (wr == wc);
  float psum[4][4];
#pragma unroll
  for (int i = 0; i < 4; i++)
#pragma unroll
    for (int r = 0; r < 4; r++) psum[i][r] = 0.f;

#pragma unroll
  for (int i = 0; i < 4; i++)
#pragma unroll
    for (int j = 0; j < 4; j++)
#pragma unroll
      for (int r = 0; r < 4; r++) {
        float e = exp2f(fmaf(acc[i][j][r], LOG2E, -C_LOG2E));
        if (diagw && (i == j) && (cl == q * 4 + r)) e = 0.f;
        psum[i][r] += e;
      }

#pragma unroll
  for (int i = 0; i < 4; i++)
#pragma unroll
    for (int r = 0; r < 4; r++) {
      float v = psum[i][r];
      v += __shfl_xor(v, 1, 64);
      v += __shfl_xor(v, 2, 64);
      v += __shfl_xor(v, 4, 64);
      v += __shfl_xor(v, 8, 64);
      if (cl == 0) atomicAdd(&rowsum[rt * 128 + wr + i * 16 + q * 4 + r], v);
    }
}

__global__ void k_finalize(const float* __restrict__ rowsum, const float* __restrict__ posbuf,
                           float* __restrict__ out) {
  __shared__ float red[4];
  const int t = threadIdx.x;
  float s = 0.f;
  for (int r = t; r < TWO_N; r += 256) s += logf(rowsum[r]);
  for (int r = t; r < N_ROWS; r += 256) s -= 2.f * posbuf[r];
  float tot = block_reduce_sum(s, red);
  if (t == 0) out[0] = tot / (float)TWO_N + INV_T;
}

extern "C" void kernel_launch(void* const* d_in, const int* in_sizes, int n_in,
                              void* d_out, int out_size, void* d_ws, size_t ws_size,
                              hipStream_t stream) {
  const float* z1 = (const float*)d_in[0];
  const float* z2 = (const float*)d_in[1];
  float* out = (float*)d_out;
  char* ws = (char*)d_ws;

  __hip_bfloat16* zn = (__hip_bfloat16*)ws;              // 8192*512*2 = 8388608 B
  float* scales = (float*)(ws + 8388608);                 // 8192*4 = 32768 B
  float* rowsum = (float*)(ws + 8421376);                 // 8192*4 = 32768 B
  float* posbuf = (float*)(ws + 8454144);                 // 4096*4 = 16384 B

  hipMemsetAsync(rowsum, 0, TWO_N * sizeof(float), stream);
  k_normalize<<<TWO_N, 256, 0, stream>>>(z1, z2, zn, scales);
  k_pos<<<N_ROWS, 256, 0, stream>>>(z1, z2, scales, posbuf);
  k_lse<<<dim3(64, 64), 256, 0, stream>>>(zn, rowsum);
  k_finalize<<<1, 256, 0, stream>>>(rowsum, posbuf, out);
}

// Round 3
// 146.645 us; speedup vs baseline: 1.3240x; 1.3240x over previous
//
#include <hip/hip_runtime.h>
#include <hip/hip_bf16.h>

#define N_ROWS 4096
#define TWO_N 8192
#define DIM 512
#define BK 32
#define INV_T 14.285714285714286f          // 1/0.07
#define LOG2E 1.4426950408889634f
#define C_LOG2E 20.60992915555662f          // (1/0.07)*log2(e)
#define INV_SQRT_T 3.7796447300922722f      // 1/sqrt(0.07)

typedef __bf16 bf16x8 __attribute__((ext_vector_type(8)));
typedef float f32x4 __attribute__((ext_vector_type(4)));

#define ASYNC_COPY16(gp, lp)                                                     \
  __builtin_amdgcn_global_load_lds((const __attribute__((address_space(1))) void*)(gp), \
                                   (__attribute__((address_space(3))) void*)(lp), 16, 0, 0)

// Fused: row norms for z1/z2, bf16 store of zhat/sqrt(T), positives in fp32.
__global__ void k_prep(const float* __restrict__ z1, const float* __restrict__ z2,
                       __hip_bfloat16* __restrict__ zn, float* __restrict__ posbuf) {
  __shared__ float red[12];
  const int r = blockIdx.x, t = threadIdx.x;
  const float* p1 = z1 + (size_t)r * DIM;
  const float* p2 = z2 + (size_t)r * DIM;
  float a1 = p1[t], b1 = p1[t + 256];
  float a2 = p2[t], b2 = p2[t + 256];
  float s1 = a1 * a1 + b1 * b1;
  float s2 = a2 * a2 + b2 * b2;
  float sd = a1 * a2 + b1 * b2;
#pragma unroll
  for (int off = 32; off > 0; off >>= 1) {
    s1 += __shfl_down(s1, off, 64);
    s2 += __shfl_down(s2, off, 64);
    sd += __shfl_down(sd, off, 64);
  }
  const int w = t >> 6;
  if ((t & 63) == 0) { red[w] = s1; red[4 + w] = s2; red[8 + w] = sd; }
  __syncthreads();
  s1 = red[0] + red[1] + red[2] + red[3];
  s2 = red[4] + red[5] + red[6] + red[7];
  sd = red[8] + red[9] + red[10] + red[11];
  float sc1 = INV_SQRT_T / fmaxf(sqrtf(s1), 1e-8f);
  float sc2 = INV_SQRT_T / fmaxf(sqrtf(s2), 1e-8f);
  zn[(size_t)r * DIM + t]                    = __float2bfloat16(a1 * sc1);
  zn[(size_t)r * DIM + t + 256]              = __float2bfloat16(b1 * sc1);
  zn[(size_t)(r + N_ROWS) * DIM + t]         = __float2bfloat16(a2 * sc2);
  zn[(size_t)(r + N_ROWS) * DIM + t + 256]   = __float2bfloat16(b2 * sc2);
  if (t == 0) posbuf[r] = sd * sc1 * sc2;   // = cos(z1_r,z2_r)/T
}

// Flash-LSE GEMM over UPPER-TRIANGLE tiles only (sim symmetric).
// Off-diagonal tile (rt<ct): row-sums -> rt rows, col-sums -> ct rows.
// Diagonal tile: row-sums only (full 128x128 computed; diag elems masked).
__global__ __launch_bounds__(256, 2) void k_lse(const __hip_bfloat16* __restrict__ Zn,
                                                float* __restrict__ rowsum) {
  __shared__ char smem[16384] __attribute__((aligned(16)));
  char* sA = smem;
  char* sB = smem + 8192;
  const int tid  = threadIdx.x;
  const int wave = tid >> 6;
  const int lane = tid & 63;
  const int cl   = lane & 15;
  const int q    = lane >> 4;

  // linear block -> (rt, ct) with rt <= ct over 64x64 tile grid
  const int b = blockIdx.x;
  int rt = (int)((129.0f - sqrtf(16641.0f - 8.0f * (float)b)) * 0.5f);
  if (rt > 63) rt = 63;
  if (rt < 0) rt = 0;
  while (rt > 0 && 64 * rt - rt * (rt - 1) / 2 > b) rt--;
  while (64 * (rt + 1) - (rt + 1) * rt / 2 <= b) rt++;
  const int ct = rt + (b - (64 * rt - rt * (rt - 1) / 2));

  const int wr = (wave >> 1) * 64;   // wave's row offset in tile
  const int wc = (wave & 1) * 64;    // wave's col offset in tile

  // Staging with XOR-swizzled k-granules: slot s holds granule
  // (row = s>>2, kq = (s&3) ^ (row&3)).  Lane loads the swizzled global
  // granule so the wave-uniform LDS dest (base + lane*16) lands it at slot s.
  const int g0 = tid, g1 = tid + 256;
  const int r0 = g0 >> 2, k0 = ((g0 & 3) ^ (r0 & 3)) * 8;
  const int r1 = g1 >> 2, k1 = ((g1 & 3) ^ (r1 & 3)) * 8;
  const size_t aoff0 = (size_t)(rt * 128 + r0) * DIM + k0;
  const size_t aoff1 = (size_t)(rt * 128 + r1) * DIM + k1;
  const size_t boff0 = (size_t)(ct * 128 + r0) * DIM + k0;
  const size_t boff1 = (size_t)(ct * 128 + r1) * DIM + k1;
  char* ldsA0 = sA + wave * 1024;
  char* ldsA1 = sA + 4096 + wave * 1024;
  char* ldsB0 = sB + wave * 1024;
  char* ldsB1 = sB + 4096 + wave * 1024;

  f32x4 acc[4][4] = {};
  const int kx = (q ^ (cl & 3)) * 8;   // swizzled k-granule for fragment reads

  for (int ks = 0; ks < DIM / BK; ks++) {
    const int ko = ks * BK;
    ASYNC_COPY16(Zn + aoff0 + ko, ldsA0);
    ASYNC_COPY16(Zn + aoff1 + ko, ldsA1);
    ASYNC_COPY16(Zn + boff0 + ko, ldsB0);
    ASYNC_COPY16(Zn + boff1 + ko, ldsB1);
    __syncthreads();

    bf16x8 af[4], bfr[4];
#pragma unroll
    for (int i = 0; i < 4; i++)
      af[i] = *reinterpret_cast<const bf16x8*>(sA + ((wr + i * 16 + cl) * BK + kx) * 2);
#pragma unroll
    for (int j = 0; j < 4; j++)
      bfr[j] = *reinterpret_cast<const bf16x8*>(sB + ((wc + j * 16 + cl) * BK + kx) * 2);
#pragma unroll
    for (int i = 0; i < 4; i++)
#pragma unroll
      for (int j = 0; j < 4; j++)
        acc[i][j] = __builtin_amdgcn_mfma_f32_16x16x32_bf16(af[i], bfr[j], acc[i][j], 0, 0, 0);
    __syncthreads();
  }

  // Epilogue: e = exp(s - C) with diagonal masked.
  // C-layout: col = cl, row = q*4 + r (within 16x16 frag (i,j)).
  const bool diagw = (rt == ct) && (wr == wc);
  float psum[4][4];
#pragma unroll
  for (int i = 0; i < 4; i++)
#pragma unroll
    for (int r = 0; r < 4; r++) psum[i][r] = 0.f;
  float colp[4] = {0.f, 0.f, 0.f, 0.f};

#pragma unroll
  for (int i = 0; i < 4; i++)
#pragma unroll
    for (int j = 0; j < 4; j++)
#pragma unroll
      for (int r = 0; r < 4; r++) {
        float e = exp2f(fmaf(acc[i][j][r], LOG2E, -C_LOG2E));
        if (diagw && (i == j) && (cl == q * 4 + r)) e = 0.f;
        psum[i][r] += e;
        colp[j] += e;
      }

  // row sums -> rt rows (reduce across cols: cl lanes)
#pragma unroll
  for (int i = 0; i < 4; i++)
#pragma unroll
    for (int r = 0; r < 4; r++) {
      float v = psum[i][r];
      v += __shfl_xor(v, 1, 64);
      v += __shfl_xor(v, 2, 64);
      v += __shfl_xor(v, 4, 64);
      v += __shfl_xor(v, 8, 64);
      if (cl == 0) atomicAdd(&rowsum[rt * 128 + wr + i * 16 + q * 4 + r], v);
    }

  // col sums -> ct rows (reduce across rows: q lanes), only off-diagonal tiles
  if (rt != ct) {
#pragma unroll
    for (int j = 0; j < 4; j++) {
      float v = colp[j];
      v += __shfl_xor(v, 16, 64);
      v += __shfl_xor(v, 32, 64);
      if (q == 0) atomicAdd(&rowsum[ct * 128 + wc + j * 16 + cl], v);
    }
  }
}

__global__ void k_finalize(const float* __restrict__ rowsum, const float* __restrict__ posbuf,
                           float* __restrict__ out) {
  __shared__ float red[4];
  const int t = threadIdx.x;
  float s = 0.f;
  for (int r = t; r < TWO_N; r += 256) s += logf(rowsum[r]);
  for (int r = t; r < N_ROWS; r += 256) s -= 2.f * posbuf[r];
#pragma unroll
  for (int off = 32; off > 0; off >>= 1) s += __shfl_down(s, off, 64);
  if ((t & 63) == 0) red[t >> 6] = s;
  __syncthreads();
  if (t == 0) out[0] = (red[0] + red[1] + red[2] + red[3]) / (float)TWO_N + INV_T;
}

extern "C" void kernel_launch(void* const* d_in, const int* in_sizes, int n_in,
                              void* d_out, int out_size, void* d_ws, size_t ws_size,
                              hipStream_t stream) {
  const float* z1 = (const float*)d_in[0];
  const float* z2 = (const float*)d_in[1];
  float* out = (float*)d_out;
  char* ws = (char*)d_ws;

  __hip_bfloat16* zn = (__hip_bfloat16*)ws;              // 8192*512*2 = 8388608 B
  float* rowsum = (float*)(ws + 8388608);                 // 8192*4 = 32768 B
  float* posbuf = (float*)(ws + 8421376);                 // 4096*4 = 16384 B

  hipMemsetAsync(rowsum, 0, TWO_N * sizeof(float), stream);
  k_prep<<<N_ROWS, 256, 0, stream>>>(z1, z2, zn, posbuf);
  k_lse<<<2080, 256, 0, stream>>>(zn, rowsum);
  k_finalize<<<1, 256, 0, stream>>>(rowsum, posbuf, out);
}

// Round 4
// 137.853 us; speedup vs baseline: 1.4084x; 1.0638x over previous
//
#include <hip/hip_runtime.h>
#include <hip/hip_bf16.h>

#define N_ROWS 4096
#define TWO_N 8192
#define DIM 512
#define BK 32
#define INV_T 14.285714285714286f          // 1/0.07
#define LOG2E 1.4426950408889634f
#define C_LOG2E 20.60992915555662f          // (1/0.07)*log2(e)
#define INV_SQRT_T 3.7796447300922722f      // 1/sqrt(0.07)

typedef __bf16 bf16x8 __attribute__((ext_vector_type(8)));
typedef float f32x4 __attribute__((ext_vector_type(4)));

#define ASYNC_COPY16(gp, lp)                                                     \
  __builtin_amdgcn_global_load_lds((const __attribute__((address_space(1))) void*)(gp), \
                                   (__attribute__((address_space(3))) void*)(lp), 16, 0, 0)

// Fused: row norms, bf16 store of zhat/sqrt(T), positives in fp32,
// plus zeroing of rowsum (8192 floats) and the final accumulator.
__global__ void k_prep(const float* __restrict__ z1, const float* __restrict__ z2,
                       __hip_bfloat16* __restrict__ zn, float* __restrict__ posbuf,
                       float* __restrict__ rowsum, float* __restrict__ acc_out) {
  __shared__ float red[12];
  const int r = blockIdx.x, t = threadIdx.x;
  if (r < 32) rowsum[r * 256 + t] = 0.f;           // 32*256 = 8192
  if (r == 32 && t == 0) acc_out[0] = 0.f;
  const float* p1 = z1 + (size_t)r * DIM;
  const float* p2 = z2 + (size_t)r * DIM;
  float a1 = p1[t], b1 = p1[t + 256];
  float a2 = p2[t], b2 = p2[t + 256];
  float s1 = a1 * a1 + b1 * b1;
  float s2 = a2 * a2 + b2 * b2;
  float sd = a1 * a2 + b1 * b2;
#pragma unroll
  for (int off = 32; off > 0; off >>= 1) {
    s1 += __shfl_down(s1, off, 64);
    s2 += __shfl_down(s2, off, 64);
    sd += __shfl_down(sd, off, 64);
  }
  const int w = t >> 6;
  if ((t & 63) == 0) { red[w] = s1; red[4 + w] = s2; red[8 + w] = sd; }
  __syncthreads();
  s1 = red[0] + red[1] + red[2] + red[3];
  s2 = red[4] + red[5] + red[6] + red[7];
  sd = red[8] + red[9] + red[10] + red[11];
  float sc1 = INV_SQRT_T / fmaxf(sqrtf(s1), 1e-8f);
  float sc2 = INV_SQRT_T / fmaxf(sqrtf(s2), 1e-8f);
  zn[(size_t)r * DIM + t]                    = __float2bfloat16(a1 * sc1);
  zn[(size_t)r * DIM + t + 256]              = __float2bfloat16(b1 * sc1);
  zn[(size_t)(r + N_ROWS) * DIM + t]         = __float2bfloat16(a2 * sc2);
  zn[(size_t)(r + N_ROWS) * DIM + t + 256]   = __float2bfloat16(b2 * sc2);
  if (t == 0) posbuf[r] = sd * sc1 * sc2;   // = cos(z1_r,z2_r)/T
}

// Flash-LSE GEMM over UPPER-TRIANGLE tiles (sim symmetric), double-buffered
// LDS with prefetch issued AFTER the barrier, and a conflict-free XOR swizzle.
// LDS layout: buf b at smem + b*16384; A tile [0,8192), B tile [8192,16384).
// Slot s (16B granules, s in [0,512)) holds granule (row = s>>2,
// kq = ((s&3) - ((s>>4)&3)) & 3)  i.e. per-row-group rotation of k-granules.
__global__ __launch_bounds__(256, 2) void k_lse(const __hip_bfloat16* __restrict__ Zn,
                                                float* __restrict__ rowsum) {
  __shared__ char smem[32768] __attribute__((aligned(16)));
  const int tid  = threadIdx.x;
  const int wave = tid >> 6;
  const int lane = tid & 63;
  const int cl   = lane & 15;
  const int q    = lane >> 4;

  // linear block -> (rt, ct) with rt <= ct over 64x64 tile grid
  const int b = blockIdx.x;
  int rt = (int)((129.0f - sqrtf(16641.0f - 8.0f * (float)b)) * 0.5f);
  if (rt > 63) rt = 63;
  if (rt < 0) rt = 0;
  while (rt > 0 && 64 * rt - rt * (rt - 1) / 2 > b) rt--;
  while (64 * (rt + 1) - (rt + 1) * rt / 2 <= b) rt++;
  const int ct = rt + (b - (64 * rt - rt * (rt - 1) / 2));

  const int wr = (wave >> 1) * 64;   // wave's row offset in tile
  const int wc = (wave & 1) * 64;    // wave's col offset in tile

  // staging: thread owns slots g0=tid, g1=tid+256 of each 128x32 tile
  const int g0 = tid, g1 = tid + 256;
  const int r0 = g0 >> 2, k0 = (((g0 & 3) - ((g0 >> 4) & 3)) & 3) * 8;
  const int r1 = g1 >> 2, k1 = (((g1 & 3) - ((g1 >> 4) & 3)) & 3) * 8;
  const size_t aoff0 = (size_t)(rt * 128 + r0) * DIM + k0;
  const size_t aoff1 = (size_t)(rt * 128 + r1) * DIM + k1;
  const size_t boff0 = (size_t)(ct * 128 + r0) * DIM + k0;
  const size_t boff1 = (size_t)(ct * 128 + r1) * DIM + k1;

  f32x4 acc[4][4] = {};
  // fragment read k-granule: col = (q + (cl>>2)) & 3 -> conflict-free phases
  const int kx = ((q + (cl >> 2)) & 3) * 8;

#define STAGE(bufi, ko)                                                    \
  {                                                                        \
    char* dA = smem + (bufi) * 16384 + wave * 1024;                        \
    char* dB = smem + (bufi) * 16384 + 8192 + wave * 1024;                 \
    ASYNC_COPY16(Zn + aoff0 + (ko), dA);                                   \
    ASYNC_COPY16(Zn + aoff1 + (ko), dA + 4096);                            \
    ASYNC_COPY16(Zn + boff0 + (ko), dB);                                   \
    ASYNC_COPY16(Zn + boff1 + (ko), dB + 4096);                            \
  }

  STAGE(0, 0);
  for (int ks = 0; ks < DIM / BK; ks++) {
    const int cur = ks & 1;
    __syncthreads();                        // drains copy issued a full iter ago
    if (ks + 1 < DIM / BK) STAGE(1 - cur, (ks + 1) * BK);

    const char* sA = smem + cur * 16384;
    const char* sB = sA + 8192;
    bf16x8 af[4], bfr[4];
#pragma unroll
    for (int i = 0; i < 4; i++)
      af[i] = *reinterpret_cast<const bf16x8*>(sA + ((wr + i * 16 + cl) * BK + kx) * 2);
#pragma unroll
    for (int j = 0; j < 4; j++)
      bfr[j] = *reinterpret_cast<const bf16x8*>(sB + ((wc + j * 16 + cl) * BK + kx) * 2);
#pragma unroll
    for (int i = 0; i < 4; i++)
#pragma unroll
      for (int j = 0; j < 4; j++)
        acc[i][j] = __builtin_amdgcn_mfma_f32_16x16x32_bf16(af[i], bfr[j], acc[i][j], 0, 0, 0);
  }
#undef STAGE

  // Epilogue: e = exp(s - C) with diagonal masked.
  // C-layout: col = cl, row = q*4 + r (within 16x16 frag (i,j)).
  const bool diagw = (rt == ct) && (wr == wc);
  float psum[4][4];
#pragma unroll
  for (int i = 0; i < 4; i++)
#pragma unroll
    for (int r = 0; r < 4; r++) psum[i][r] = 0.f;
  float colp[4] = {0.f, 0.f, 0.f, 0.f};

#pragma unroll
  for (int i = 0; i < 4; i++)
#pragma unroll
    for (int j = 0; j < 4; j++)
#pragma unroll
      for (int r = 0; r < 4; r++) {
        float e = exp2f(fmaf(acc[i][j][r], LOG2E, -C_LOG2E));
        if (diagw && (i == j) && (cl == q * 4 + r)) e = 0.f;
        psum[i][r] += e;
        colp[j] += e;
      }

  // row sums -> rt rows (reduce across cols: cl lanes)
#pragma unroll
  for (int i = 0; i < 4; i++)
#pragma unroll
    for (int r = 0; r < 4; r++) {
      float v = psum[i][r];
      v += __shfl_xor(v, 1, 64);
      v += __shfl_xor(v, 2, 64);
      v += __shfl_xor(v, 4, 64);
      v += __shfl_xor(v, 8, 64);
      if (cl == 0) atomicAdd(&rowsum[rt * 128 + wr + i * 16 + q * 4 + r], v);
    }

  // col sums -> ct rows (reduce across rows: q lanes), only off-diagonal tiles
  if (rt != ct) {
#pragma unroll
    for (int j = 0; j < 4; j++) {
      float v = colp[j];
      v += __shfl_xor(v, 16, 64);
      v += __shfl_xor(v, 32, 64);
      if (q == 0) atomicAdd(&rowsum[ct * 128 + wc + j * 16 + cl], v);
    }
  }
}

// Parallel finalize: 32 blocks reduce log(rowsum) - 2*pos into acc.
__global__ void k_final1(const float* __restrict__ rowsum, const float* __restrict__ posbuf,
                         float* __restrict__ acc_out) {
  __shared__ float red[4];
  const int t = threadIdx.x;
  const int row = blockIdx.x * 256 + t;
  float s = logf(rowsum[row]);
  if (row < N_ROWS) s -= 2.f * posbuf[row];
#pragma unroll
  for (int off = 32; off > 0; off >>= 1) s += __shfl_down(s, off, 64);
  if ((t & 63) == 0) red[t >> 6] = s;
  __syncthreads();
  if (t == 0) atomicAdd(acc_out, red[0] + red[1] + red[2] + red[3]);
}

__global__ void k_final2(const float* __restrict__ acc_out, float* __restrict__ out) {
  out[0] = acc_out[0] / (float)TWO_N + INV_T;
}

extern "C" void kernel_launch(void* const* d_in, const int* in_sizes, int n_in,
                              void* d_out, int out_size, void* d_ws, size_t ws_size,
                              hipStream_t stream) {
  const float* z1 = (const float*)d_in[0];
  const float* z2 = (const float*)d_in[1];
  float* out = (float*)d_out;
  char* ws = (char*)d_ws;

  __hip_bfloat16* zn = (__hip_bfloat16*)ws;              // 8192*512*2 = 8388608 B
  float* rowsum = (float*)(ws + 8388608);                 // 8192*4 = 32768 B
  float* posbuf = (float*)(ws + 8421376);                 // 4096*4 = 16384 B
  float* acc    = (float*)(ws + 8437760);                 // 4 B

  k_prep<<<N_ROWS, 256, 0, stream>>>(z1, z2, zn, posbuf, rowsum, acc);
  k_lse<<<2080, 256, 0, stream>>>(zn, rowsum);
  k_final1<<<32, 256, 0, stream>>>(rowsum, posbuf, acc);
  k_final2<<<1, 1, 0, stream>>>(acc, out);
}